// Round 3
// baseline (232.132 us; speedup 1.0000x reference)
//
#include <hip/hip_runtime.h>
#include <math.h>

#define H 1024
#define B 32
#define S 8192

// --- Kernel 1: v[b,h] = sum_k dec[b,k] * W[k,h]  (tiny GEMV, W L2-resident) ---
// grid = B*H/256 = 128 blocks, 256 threads. Block covers one (b, 256-wide h-chunk):
// dec row address is block-uniform -> scalar loads; W reads coalesced across lanes.
__global__ __launch_bounds__(256) void vW_kernel(const float* __restrict__ dec,
                                                 const float* __restrict__ W,
                                                 float* __restrict__ v) {
    const int b = blockIdx.x >> 2;                         // 4 blocks per b (H/256)
    const int h = ((blockIdx.x & 3) << 8) + threadIdx.x;
    const float* __restrict__ dr = dec + b * H;
    float acc = 0.f;
    #pragma unroll 8
    for (int k = 0; k < H; ++k)
        acc = fmaf(dr[k], W[k * H + h], acc);
    v[b * H + h] = acc;
}

// --- Kernel 2: e[b,s] = v[b] . enc[s,b,:]  (the 1.07 GB streaming pass) ---
// One wave per (s,b). wave = s*B + b, so enc row offset = wave*H (contiguous 4 KB).
// 16 floats/lane via 4x float4 -> 1 KB per load instruction per wave. v[b] hits L1.
__global__ __launch_bounds__(256) void energy_kernel(const float* __restrict__ enc,
                                                     const float* __restrict__ v,
                                                     float* __restrict__ e) {
    const int wave = (blockIdx.x << 2) + (threadIdx.x >> 6);
    const int lane = threadIdx.x & 63;
    const int b = wave & (B - 1);
    const int s = wave >> 5;  // wave / B
    const float4* __restrict__ ep = (const float4*)(enc + (size_t)wave * H);
    const float4* __restrict__ vp = (const float4*)(v + b * H);
    float acc = 0.f;
    #pragma unroll
    for (int c = 0; c < 4; ++c) {
        const float4 ev = ep[c * 64 + lane];
        const float4 vv = vp[c * 64 + lane];
        acc = fmaf(ev.x, vv.x, acc);
        acc = fmaf(ev.y, vv.y, acc);
        acc = fmaf(ev.z, vv.z, acc);
        acc = fmaf(ev.w, vv.w, acc);
    }
    #pragma unroll
    for (int off = 32; off; off >>= 1) acc += __shfl_xor(acc, off, 64);
    if (lane == 0) e[b * S + s] = acc;
}

// --- Kernel 3: row softmax over s, in place in d_out. One block per b. ---
// 8192 values live in 32 registers/thread; single global read + single write.
__global__ __launch_bounds__(256) void softmax_kernel(float* __restrict__ e) {
    __shared__ float red[4];
    float* __restrict__ row = e + blockIdx.x * S;
    const int t = threadIdx.x;
    float vals[S / 256];

    float m = -INFINITY;
    #pragma unroll
    for (int i = 0; i < S / 256; ++i) {
        vals[i] = row[i * 256 + t];
        m = fmaxf(m, vals[i]);
    }
    #pragma unroll
    for (int off = 32; off; off >>= 1) m = fmaxf(m, __shfl_xor(m, off, 64));
    if ((t & 63) == 0) red[t >> 6] = m;
    __syncthreads();
    m = fmaxf(fmaxf(red[0], red[1]), fmaxf(red[2], red[3]));

    float sum = 0.f;
    #pragma unroll
    for (int i = 0; i < S / 256; ++i) {
        vals[i] = __expf(vals[i] - m);
        sum += vals[i];
    }
    #pragma unroll
    for (int off = 32; off; off >>= 1) sum += __shfl_xor(sum, off, 64);
    __syncthreads();  // red[] reuse hazard
    if ((t & 63) == 0) red[t >> 6] = sum;
    __syncthreads();
    sum = red[0] + red[1] + red[2] + red[3];

    const float inv = 1.f / sum;
    #pragma unroll
    for (int i = 0; i < S / 256; ++i)
        row[i * 256 + t] = vals[i] * inv;
}

extern "C" void kernel_launch(void* const* d_in, const int* in_sizes, int n_in,
                              void* d_out, int out_size, void* d_ws, size_t ws_size,
                              hipStream_t stream) {
    const float* dec  = (const float*)d_in[0];  // [B, H]
    const float* enc  = (const float*)d_in[1];  // [S, B, H]
    const float* W    = (const float*)d_in[2];  // [H, H]
    // d_in[3] = bias [H] — UNUSED: dec·bias is constant per row b, cancels in softmax.
    float* out = (float*)d_out;                 // [B, S] fp32
    float* v   = (float*)d_ws;                  // [B, H] scratch, 128 KB

    vW_kernel    <<<(B * H) / 256, 256, 0, stream>>>(dec, W, v);
    energy_kernel<<<(S * B) / 4,   256, 0, stream>>>(enc, v, out);
    softmax_kernel<<<B,            256, 0, stream>>>(out);
}

// Round 4
// 206.164 us; speedup vs baseline: 1.1260x; 1.1260x over previous
//
#include <hip/hip_runtime.h>
#include <math.h>

#define H 1024
#define B 32
#define S 8192
#define R 8   // rows (s values) per wave in energy_kernel

// --- Kernel 1: v[b,h] = sum_k dec[b,k] * W[k,h] ---
// 1024 blocks = (b, 32-wide h chunk); 256 threads = 32 h x 8 k-slices (128 k each).
// 8x more parallelism + 8x shorter dependent load chain than the round-2 version.
__global__ __launch_bounds__(256) void vW_kernel(const float* __restrict__ dec,
                                                 const float* __restrict__ W,
                                                 float* __restrict__ v) {
    const int b  = blockIdx.x >> 5;
    const int hb = (blockIdx.x & 31) << 5;
    const int ho = threadIdx.x & 31;
    const int ks = threadIdx.x >> 5;           // 0..7
    const float* __restrict__ dr = dec + b * H + ks * 128;
    const float* __restrict__ wp = W + (size_t)(ks * 128) * H + hb + ho;
    float acc = 0.f;
    #pragma unroll 8
    for (int k = 0; k < 128; ++k)
        acc = fmaf(dr[k], wp[k * H], acc);
    __shared__ float red[8][32];
    red[ks][ho] = acc;
    __syncthreads();
    if (threadIdx.x < 32) {
        float s = 0.f;
        #pragma unroll
        for (int i = 0; i < 8; ++i) s += red[i][threadIdx.x];
        v[b * H + hb + threadIdx.x] = s;
    }
}

// Fold two 64-lane accumulators at butterfly mask m:
// lanes with (lane&m)==0 end holding u summed over the pair, others hold v's sum.
__device__ __forceinline__ float merge2(float u, float v, int m, int lane) {
    float sent = (lane & m) ? u : v;      // give partner what it needs
    float recv = __shfl_xor(sent, m, 64);
    return ((lane & m) ? v : u) + recv;
}

// --- Kernel 2: e[b,s] = v[b] . enc[s,b,:]  (the 1.07 GB streaming pass) ---
// One wave per (b, 8 consecutive s). v[b] loaded once into 16 VGPRs, reused 8x.
// Tree-merge leaves row r's full sum in lanes with (lane&7)==r -> one 32B store.
__global__ __launch_bounds__(256) void energy_kernel(const float* __restrict__ enc,
                                                     const float* __restrict__ vg,
                                                     float* __restrict__ e) {
    const int wave = (blockIdx.x << 2) + (threadIdx.x >> 6);
    const int lane = threadIdx.x & 63;
    const int b  = wave & (B - 1);
    const int s0 = (wave >> 5) * R;

    const float4* __restrict__ vp = (const float4*)(vg + b * H);
    float4 vr[4];
    #pragma unroll
    for (int c = 0; c < 4; ++c) vr[c] = vp[c * 64 + lane];

    float acc[R];
    #pragma unroll
    for (int r = 0; r < R; ++r) {
        const float4* __restrict__ ep =
            (const float4*)(enc + ((size_t)(s0 + r) * B + b) * H);
        float a = 0.f;
        #pragma unroll
        for (int c = 0; c < 4; ++c) {
            const float4 ev = ep[c * 64 + lane];
            a = fmaf(ev.x, vr[c].x, a);
            a = fmaf(ev.y, vr[c].y, a);
            a = fmaf(ev.z, vr[c].z, a);
            a = fmaf(ev.w, vr[c].w, a);
        }
        acc[r] = a;
    }

    // 8 accs x 64 lanes -> lane L holds full sum of acc[L&7]  (10 shuffles total)
    float c0 = merge2(acc[0], acc[1], 1, lane);
    float c1 = merge2(acc[2], acc[3], 1, lane);
    float c2 = merge2(acc[4], acc[5], 1, lane);
    float c3 = merge2(acc[6], acc[7], 1, lane);
    float d0 = merge2(c0, c1, 2, lane);
    float d1 = merge2(c2, c3, 2, lane);
    float f  = merge2(d0, d1, 4, lane);
    f += __shfl_xor(f, 8, 64);
    f += __shfl_xor(f, 16, 64);
    f += __shfl_xor(f, 32, 64);

    if (lane < R) e[b * S + s0 + lane] = f;   // 32 B coalesced
}

// --- Kernel 3: row softmax over s, in place in d_out. One 1024-thread block per b. ---
__global__ __launch_bounds__(1024) void softmax_kernel(float* __restrict__ e) {
    __shared__ float red[16];
    float4* __restrict__ r4 = (float4*)(e + blockIdx.x * S);
    const int t = threadIdx.x;

    float4 a = r4[t];
    float4 c = r4[1024 + t];

    float m = fmaxf(fmaxf(fmaxf(a.x, a.y), fmaxf(a.z, a.w)),
                    fmaxf(fmaxf(c.x, c.y), fmaxf(c.z, c.w)));
    #pragma unroll
    for (int off = 32; off; off >>= 1) m = fmaxf(m, __shfl_xor(m, off, 64));
    if ((t & 63) == 0) red[t >> 6] = m;
    __syncthreads();
    #pragma unroll
    for (int i = 0; i < 16; ++i) m = fmaxf(m, red[i]);

    a.x = __expf(a.x - m); a.y = __expf(a.y - m);
    a.z = __expf(a.z - m); a.w = __expf(a.w - m);
    c.x = __expf(c.x - m); c.y = __expf(c.y - m);
    c.z = __expf(c.z - m); c.w = __expf(c.w - m);
    float sum = (a.x + a.y + a.z + a.w) + (c.x + c.y + c.z + c.w);
    #pragma unroll
    for (int off = 32; off; off >>= 1) sum += __shfl_xor(sum, off, 64);
    __syncthreads();   // red[] reuse hazard
    if ((t & 63) == 0) red[t >> 6] = sum;
    __syncthreads();
    sum = 0.f;
    #pragma unroll
    for (int i = 0; i < 16; ++i) sum += red[i];

    const float inv = 1.f / sum;
    a.x *= inv; a.y *= inv; a.z *= inv; a.w *= inv;
    c.x *= inv; c.y *= inv; c.z *= inv; c.w *= inv;
    r4[t] = a;
    r4[1024 + t] = c;
}

extern "C" void kernel_launch(void* const* d_in, const int* in_sizes, int n_in,
                              void* d_out, int out_size, void* d_ws, size_t ws_size,
                              hipStream_t stream) {
    const float* dec  = (const float*)d_in[0];  // [B, H]
    const float* enc  = (const float*)d_in[1];  // [S, B, H]
    const float* W    = (const float*)d_in[2];  // [H, H]
    // d_in[3] = bias [H] — UNUSED: dec·bias is constant per row b, cancels in softmax.
    float* out = (float*)d_out;                 // [B, S] fp32
    float* v   = (float*)d_ws;                  // [B, H] scratch, 128 KB

    vW_kernel     <<<B * (H / 32),      256,  0, stream>>>(dec, W, v);
    energy_kernel <<<(S * B / R) / 4,   256,  0, stream>>>(enc, v, out);
    softmax_kernel<<<B,                 1024, 0, stream>>>(out);
}

// Round 6
// 182.920 us; speedup vs baseline: 1.2690x; 1.1271x over previous
//
#include <hip/hip_runtime.h>
#include <math.h>

#define H 1024
#define B 32
#define S 8192
#define R 8   // rows (s values) per wave in energy_kernel

// clang-native 4-float vector: __builtin_nontemporal_load requires a native
// scalar/vector pointee (HIP_vector_type float4 is rejected on gfx950).
typedef float nf4 __attribute__((ext_vector_type(4)));

// --- Kernel 1: v[b,h] = sum_k dec[b,k] * W[k,h] ---
// 256 blocks = (b, 128-wide h chunk); 256 threads = 32 float4-h x 8 k-slices.
// float4 W loads: 512 B per instruction per 32-lane group.
__global__ __launch_bounds__(256) void vW_kernel(const float* __restrict__ dec,
                                                 const float* __restrict__ W,
                                                 float* __restrict__ v) {
    const int b  = blockIdx.x >> 3;          // 8 h-chunks per b
    const int hb = (blockIdx.x & 7) << 7;    // 128-col chunk
    const int hq = threadIdx.x & 31;         // float4 index within chunk
    const int ks = threadIdx.x >> 5;         // 0..7, 128 k each
    const float* __restrict__ dr = dec + b * H + ks * 128;
    const float4* __restrict__ wp =
        (const float4*)(W + (size_t)(ks * 128) * H + hb) + hq;
    float4 acc = {0.f, 0.f, 0.f, 0.f};
    #pragma unroll 4
    for (int k = 0; k < 128; ++k) {
        const float4 w = wp[k * (H / 4)];
        const float d = dr[k];
        acc.x = fmaf(d, w.x, acc.x);
        acc.y = fmaf(d, w.y, acc.y);
        acc.z = fmaf(d, w.z, acc.z);
        acc.w = fmaf(d, w.w, acc.w);
    }
    __shared__ float4 red[8][32];
    red[ks][hq] = acc;
    __syncthreads();
    if (threadIdx.x < 32) {
        float4 s = red[0][threadIdx.x];
        #pragma unroll
        for (int i = 1; i < 8; ++i) {
            const float4 p = red[i][threadIdx.x];
            s.x += p.x; s.y += p.y; s.z += p.z; s.w += p.w;
        }
        ((float4*)(v + b * H + hb))[threadIdx.x] = s;
    }
}

// Fold two 64-lane accumulators at butterfly mask m:
// lanes with (lane&m)==0 end holding u summed over the pair, others hold v's sum.
__device__ __forceinline__ float merge2(float u, float v, int m, int lane) {
    float sent = (lane & m) ? u : v;      // give partner what it needs
    float recv = __shfl_xor(sent, m, 64);
    return ((lane & m) ? v : u) + recv;
}

// --- Kernel 2: e[b,s] = v[b] . enc[s,b,:]  (the 1.07 GB streaming pass) ---
// One wave per (b, 8 consecutive s). v[b] loaded once into 16 VGPRs, reused 8x.
// enc loads nontemporal (zero reuse stream). Fully unrolled so all 32 row loads
// can be hoisted/pipelined by the scheduler.
__global__ __launch_bounds__(256) void energy_kernel(const float* __restrict__ enc,
                                                     const float* __restrict__ vg,
                                                     float* __restrict__ e) {
    const int wave = (blockIdx.x << 2) + (threadIdx.x >> 6);
    const int lane = threadIdx.x & 63;
    const int b  = wave & (B - 1);
    const int s0 = (wave >> 5) * R;

    const float4* __restrict__ vp = (const float4*)(vg + b * H);
    float4 vr[4];
    #pragma unroll
    for (int c = 0; c < 4; ++c) vr[c] = vp[c * 64 + lane];

    // row r base (in float4): ((s0+r)*B + b)*H/4 = base + r*(B*H/4)
    const nf4* __restrict__ ep =
        (const nf4*)(enc + ((size_t)s0 * B + b) * H) + lane;

    float acc[R];
    #pragma unroll
    for (int r = 0; r < R; ++r) {
        const nf4* __restrict__ rp = ep + (size_t)r * (B * H / 4);
        float a = 0.f;
        #pragma unroll
        for (int c = 0; c < 4; ++c) {
            const nf4 ev = __builtin_nontemporal_load(rp + c * 64);
            a = fmaf(ev.x, vr[c].x, a);
            a = fmaf(ev.y, vr[c].y, a);
            a = fmaf(ev.z, vr[c].z, a);
            a = fmaf(ev.w, vr[c].w, a);
        }
        acc[r] = a;
    }

    // 8 accs x 64 lanes -> lane L holds full sum of acc[L&7]  (10 shuffles total)
    float c0 = merge2(acc[0], acc[1], 1, lane);
    float c1 = merge2(acc[2], acc[3], 1, lane);
    float c2 = merge2(acc[4], acc[5], 1, lane);
    float c3 = merge2(acc[6], acc[7], 1, lane);
    float d0 = merge2(c0, c1, 2, lane);
    float d1 = merge2(c2, c3, 2, lane);
    float f  = merge2(d0, d1, 4, lane);
    f += __shfl_xor(f, 8, 64);
    f += __shfl_xor(f, 16, 64);
    f += __shfl_xor(f, 32, 64);

    if (lane < R) e[b * S + s0 + lane] = f;   // 32 B coalesced
}

// --- Kernel 3: row softmax over s, in place in d_out. One 1024-thread block per b. ---
__global__ __launch_bounds__(1024) void softmax_kernel(float* __restrict__ e) {
    __shared__ float red[16];
    float4* __restrict__ r4 = (float4*)(e + blockIdx.x * S);
    const int t = threadIdx.x;

    float4 a = r4[t];
    float4 c = r4[1024 + t];

    float m = fmaxf(fmaxf(fmaxf(a.x, a.y), fmaxf(a.z, a.w)),
                    fmaxf(fmaxf(c.x, c.y), fmaxf(c.z, c.w)));
    #pragma unroll
    for (int off = 32; off; off >>= 1) m = fmaxf(m, __shfl_xor(m, off, 64));
    if ((t & 63) == 0) red[t >> 6] = m;
    __syncthreads();
    #pragma unroll
    for (int i = 0; i < 16; ++i) m = fmaxf(m, red[i]);

    a.x = __expf(a.x - m); a.y = __expf(a.y - m);
    a.z = __expf(a.z - m); a.w = __expf(a.w - m);
    c.x = __expf(c.x - m); c.y = __expf(c.y - m);
    c.z = __expf(c.z - m); c.w = __expf(c.w - m);
    float sum = (a.x + a.y + a.z + a.w) + (c.x + c.y + c.z + c.w);
    #pragma unroll
    for (int off = 32; off; off >>= 1) sum += __shfl_xor(sum, off, 64);
    __syncthreads();   // red[] reuse hazard
    if ((t & 63) == 0) red[t >> 6] = sum;
    __syncthreads();
    sum = 0.f;
    #pragma unroll
    for (int i = 0; i < 16; ++i) sum += red[i];

    const float inv = 1.f / sum;
    a.x *= inv; a.y *= inv; a.z *= inv; a.w *= inv;
    c.x *= inv; c.y *= inv; c.z *= inv; c.w *= inv;
    r4[t] = a;
    r4[1024 + t] = c;
}

extern "C" void kernel_launch(void* const* d_in, const int* in_sizes, int n_in,
                              void* d_out, int out_size, void* d_ws, size_t ws_size,
                              hipStream_t stream) {
    const float* dec  = (const float*)d_in[0];  // [B, H]
    const float* enc  = (const float*)d_in[1];  // [S, B, H]
    const float* W    = (const float*)d_in[2];  // [H, H]
    // d_in[3] = bias [H] — UNUSED: dec·bias is constant per row b, cancels in softmax.
    float* out = (float*)d_out;                 // [B, S] fp32
    float* v   = (float*)d_ws;                  // [B, H] scratch, 128 KB

    vW_kernel     <<<B * (H / 128),     256,  0, stream>>>(dec, W, v);
    energy_kernel <<<(S * B / R) / 4,   256,  0, stream>>>(enc, v, out);
    softmax_kernel<<<B,                 1024, 0, stream>>>(out);
}